// Round 1
// baseline (1361.483 us; speedup 1.0000x reference)
//
#include <hip/hip_runtime.h>

#define N_NODES 50000
#define N_EDGES 640000
#define DFEAT   128

// workspace layout (float offsets)
#define OFF_HTMP 0
#define OFF_HOUT 6400000
#define OFF_DEG  12800000   // int[50000]
#define OFF_DINV 12850000
#define OFF_E    12900000
#define OFF_Q    12950000
#define OFF_SCAL 13000000   // [0]=EminBits(int) [1]=S0 [2]=S1

__global__ __launch_bounds__(256) void k_init(float* ws) {
    int i = blockIdx.x * 256 + threadIdx.x;
    if (i < N_NODES) {
        ((int*)(ws + OFF_DEG))[i] = 0;
        ws[OFF_E + i] = 0.f;
    }
    if (i == 0) {
        ((int*)(ws + OFF_SCAL))[0] = 0x7F7FFFFF;  // FLT_MAX bits
        ws[OFF_SCAL + 1] = 0.f;
        ws[OFF_SCAL + 2] = 0.f;
    }
}

__global__ __launch_bounds__(256) void k_deg(const int* __restrict__ dst, int* __restrict__ deg) {
    int e = blockIdx.x * 256 + threadIdx.x;
    atomicAdd(&deg[dst[e]], 1);
}

// h = x @ W.  x:[N,128], W:[128,128] row-major (k-major). 64x64 tile, 4x4 per thread.
__global__ __launch_bounds__(256) void k_gemm(const float* __restrict__ x,
                                              const float* __restrict__ W,
                                              float* __restrict__ h) {
    __shared__ float xs[64 * 132];    // padded: bank spread
    __shared__ float wsm[128 * 64];
    int r0 = blockIdx.x * 64;
    int c0 = blockIdx.y * 64;
    int tid = threadIdx.x;

    #pragma unroll
    for (int i = 0; i < 8; i++) {
        int slot = tid + i * 256;          // 2048 float4 slots
        int row = slot >> 5, k4 = slot & 31;
        float4 v = make_float4(0.f, 0.f, 0.f, 0.f);
        int gr = r0 + row;
        if (gr < N_NODES) v = *(const float4*)(x + gr * 128 + k4 * 4);
        *(float4*)(xs + row * 132 + k4 * 4) = v;
    }
    #pragma unroll
    for (int i = 0; i < 8; i++) {
        int slot = tid + i * 256;
        int k = slot >> 4, c4 = slot & 15;
        *(float4*)(wsm + k * 64 + c4 * 4) = *(const float4*)(W + k * 128 + c0 + c4 * 4);
    }
    __syncthreads();

    int tx = tid & 15, ty = tid >> 4;
    float acc[4][4];
    #pragma unroll
    for (int i = 0; i < 4; i++)
        #pragma unroll
        for (int j = 0; j < 4; j++) acc[i][j] = 0.f;

    for (int k = 0; k < 128; k++) {
        float4 wv = *(const float4*)(wsm + k * 64 + tx * 4);
        float xr[4];
        #pragma unroll
        for (int i = 0; i < 4; i++) xr[i] = xs[(ty * 4 + i) * 132 + k];
        #pragma unroll
        for (int i = 0; i < 4; i++) {
            acc[i][0] += xr[i] * wv.x;
            acc[i][1] += xr[i] * wv.y;
            acc[i][2] += xr[i] * wv.z;
            acc[i][3] += xr[i] * wv.w;
        }
    }
    #pragma unroll
    for (int i = 0; i < 4; i++) {
        int gr = r0 + ty * 4 + i;
        if (gr < N_NODES) {
            *(float4*)(h + gr * 128 + c0 + tx * 4) =
                make_float4(acc[i][0], acc[i][1], acc[i][2], acc[i][3]);
        }
    }
}

__global__ __launch_bounds__(256) void k_dinv(const int* __restrict__ deg, float* __restrict__ dinv) {
    int i = blockIdx.x * 256 + threadIdx.x;
    if (i < N_NODES) dinv[i] = rsqrtf((float)(deg[i] + 1));  // +1 self-loop
}

// hout[i][j] = b[j] + htmp[i][j]*dinv[i]^2   (self-loop term + bias as init)
__global__ __launch_bounds__(256) void k_hout_init(const float* __restrict__ htmp,
                                                   const float* __restrict__ dinv,
                                                   const float* __restrict__ b,
                                                   float* __restrict__ hout) {
    int gid = blockIdx.x * 256 + threadIdx.x;
    int i = gid >> 5, j4 = (gid & 31) * 4;
    float s = dinv[i]; s = s * s;
    float4 hv = *(const float4*)(htmp + i * 128 + j4);
    float4 bv = *(const float4*)(b + j4);
    float4 o = make_float4(bv.x + hv.x * s, bv.y + hv.y * s, bv.z + hv.z * s, bv.w + hv.w * s);
    *(float4*)(hout + i * 128 + j4) = o;
}

// per edge: hout[d] += htmp[s] * dinv[s]*dinv[d].  32 lanes/edge, 4 floats/lane.
__global__ __launch_bounds__(256) void k_scatter(const int* __restrict__ src,
                                                 const int* __restrict__ dst,
                                                 const float* __restrict__ htmp,
                                                 const float* __restrict__ dinv,
                                                 float* __restrict__ hout) {
    int gid = blockIdx.x * 256 + threadIdx.x;
    int e = gid >> 5, j4 = (gid & 31) * 4;
    int s = src[e], d = dst[e];
    float norm = dinv[s] * dinv[d];
    float4 hv = *(const float4*)(htmp + s * 128 + j4);
    float* o = hout + d * 128 + j4;
    atomicAdd(o + 0, hv.x * norm);
    atomicAdd(o + 1, hv.y * norm);
    atomicAdd(o + 2, hv.z * norm);
    atomicAdd(o + 3, hv.w * norm);
}

// E[d] += ||hout[s]-hout[d]||^2 per edge
__global__ __launch_bounds__(256) void k_energy(const int* __restrict__ src,
                                                const int* __restrict__ dst,
                                                const float* __restrict__ hout,
                                                float* __restrict__ E) {
    int gid = blockIdx.x * 256 + threadIdx.x;
    int e = gid >> 5, j4 = (gid & 31) * 4;
    int s = src[e], d = dst[e];
    float4 a = *(const float4*)(hout + s * 128 + j4);
    float4 b = *(const float4*)(hout + d * 128 + j4);
    float dx = a.x - b.x, dy = a.y - b.y, dz = a.z - b.z, dw = a.w - b.w;
    float v = dx * dx + dy * dy + dz * dz + dw * dw;
    #pragma unroll
    for (int off = 16; off; off >>= 1) v += __shfl_xor(v, off);
    if ((gid & 31) == 0) atomicAdd(&E[d], v);
}

__global__ __launch_bounds__(256) void k_emin(const float* __restrict__ E, int* __restrict__ scal) {
    __shared__ float sh[4];
    int i = blockIdx.x * 256 + threadIdx.x;
    float v = 3.402823466e38f;
    if (i < N_NODES) v = E[i];
    #pragma unroll
    for (int off = 32; off; off >>= 1) v = fminf(v, __shfl_xor(v, off));
    int lane = threadIdx.x & 63, wid = threadIdx.x >> 6;
    if (lane == 0) sh[wid] = v;
    __syncthreads();
    if (threadIdx.x == 0) {
        float m = fminf(fminf(sh[0], sh[1]), fminf(sh[2], sh[3]));
        atomicMin(scal, __float_as_int(m));  // valid: E >= 0
    }
}

__global__ __launch_bounds__(256) void k_sums(const float* __restrict__ E,
                                              const float* __restrict__ temp,
                                              const int* __restrict__ scal,
                                              float* __restrict__ S) {
    __shared__ float sh0[4], sh1[4];
    float Emin = __int_as_float(scal[0]);
    float T = temp[0];
    int i = blockIdx.x * 256 + threadIdx.x;
    float s0 = 0.f, s1 = 0.f;
    if (i < N_NODES) {
        float dd = (Emin - E[i]) / T;
        float ed = __expf(dd);
        s0 = ed; s1 = ed * dd;
    }
    #pragma unroll
    for (int off = 32; off; off >>= 1) { s0 += __shfl_xor(s0, off); s1 += __shfl_xor(s1, off); }
    int lane = threadIdx.x & 63, wid = threadIdx.x >> 6;
    if (lane == 0) { sh0[wid] = s0; sh1[wid] = s1; }
    __syncthreads();
    if (threadIdx.x == 0) {
        atomicAdd(&S[0], sh0[0] + sh0[1] + sh0[2] + sh0[3]);
        atomicAdd(&S[1], sh1[0] + sh1[1] + sh1[2] + sh1[3]);
    }
}

// q_i = (e^dd/S0)*(dd - S1/S0)/T   where dd=(Emin-E_i)/T
__global__ __launch_bounds__(256) void k_q(const float* __restrict__ E,
                                           const float* __restrict__ temp,
                                           const float* __restrict__ scal,
                                           float* __restrict__ q) {
    int i = blockIdx.x * 256 + threadIdx.x;
    if (i >= N_NODES) return;
    float Emin = __int_as_float(((const int*)scal)[0]);
    float S0 = scal[1], S1 = scal[2];
    float T = temp[0];
    float dd = (Emin - E[i]) / T;
    q[i] = (__expf(dd) / S0) * (dd - S1 / S0) / T;
}

__global__ __launch_bounds__(256) void k_copy(const float* __restrict__ hout, float* __restrict__ out) {
    int gid = blockIdx.x * 256 + threadIdx.x;
    *(float4*)(out + gid * 4) = *(const float4*)(hout + gid * 4);
}

// per edge: vec = 2*w*q[d]*(h_s - h_d); out[s] += vec; out[d] -= vec.  Skip q==0 (most edges).
__global__ __launch_bounds__(256) void k_grad(const int* __restrict__ src,
                                              const int* __restrict__ dst,
                                              const float* __restrict__ hout,
                                              const float* __restrict__ q,
                                              const float* __restrict__ weight,
                                              float* __restrict__ out) {
    int gid = blockIdx.x * 256 + threadIdx.x;
    int e = gid >> 5, j4 = (gid & 31) * 4;
    int d = dst[e];
    float qd = q[d];
    if (qd == 0.f) return;
    int s = src[e];
    float c = 2.f * weight[0] * qd;
    float4 a = *(const float4*)(hout + s * 128 + j4);
    float4 b = *(const float4*)(hout + d * 128 + j4);
    float vx = c * (a.x - b.x), vy = c * (a.y - b.y), vz = c * (a.z - b.z), vw = c * (a.w - b.w);
    float* os = out + s * 128 + j4;
    float* od = out + d * 128 + j4;
    atomicAdd(os + 0, vx); atomicAdd(os + 1, vy); atomicAdd(os + 2, vz); atomicAdd(os + 3, vw);
    atomicAdd(od + 0, -vx); atomicAdd(od + 1, -vy); atomicAdd(od + 2, -vz); atomicAdd(od + 3, -vw);
}

extern "C" void kernel_launch(void* const* d_in, const int* in_sizes, int n_in,
                              void* d_out, int out_size, void* d_ws, size_t ws_size,
                              hipStream_t stream) {
    const float* x      = (const float*)d_in[0];
    const int*   ei     = (const int*)d_in[1];
    const float* weight = (const float*)d_in[2];
    const float* temp   = (const float*)d_in[3];
    const float* W      = (const float*)d_in[4];
    const float* b      = (const float*)d_in[5];
    float* out = (float*)d_out;
    float* ws  = (float*)d_ws;

    const int* src = ei;
    const int* dst = ei + N_EDGES;

    float* htmp = ws + OFF_HTMP;
    float* hout = ws + OFF_HOUT;
    int*   deg  = (int*)(ws + OFF_DEG);
    float* dinv = ws + OFF_DINV;
    float* Earr = ws + OFF_E;
    float* qarr = ws + OFF_Q;
    float* scal = ws + OFF_SCAL;

    k_init<<<196, 256, 0, stream>>>(ws);
    k_deg<<<N_EDGES / 256, 256, 0, stream>>>(dst, deg);
    k_gemm<<<dim3(782, 2), 256, 0, stream>>>(x, W, htmp);
    k_dinv<<<196, 256, 0, stream>>>(deg, dinv);
    k_hout_init<<<(N_NODES * 32) / 256, 256, 0, stream>>>(htmp, dinv, b, hout);
    k_scatter<<<(N_EDGES * 32) / 256, 256, 0, stream>>>(src, dst, htmp, dinv, hout);
    k_energy<<<(N_EDGES * 32) / 256, 256, 0, stream>>>(src, dst, hout, Earr);
    k_emin<<<196, 256, 0, stream>>>(Earr, (int*)scal);
    k_sums<<<196, 256, 0, stream>>>(Earr, temp, (const int*)scal, scal + 1);
    k_q<<<196, 256, 0, stream>>>(Earr, temp, scal, qarr);
    k_copy<<<(N_NODES * 128 / 4) / 256, 256, 0, stream>>>(hout, out);
    k_grad<<<(N_EDGES * 32) / 256, 256, 0, stream>>>(src, dst, hout, qarr, weight, out);
}

// Round 2
// 336.535 us; speedup vs baseline: 4.0456x; 4.0456x over previous
//
#include <hip/hip_runtime.h>

#define N_NODES 50000
#define N_EDGES 640000

// workspace layout (float/int offsets, 4B units)
#define OFF_HTMP     0          // float[6400000]
#define OFF_DEG      6400000    // int[50000]
#define OFF_ROWSTART 6450000    // int[50001]
#define OFF_CURSOR   6500016    // int[50000]
#define OFF_DINV     6550016    // float[50000]
#define OFF_E        6600016    // float[50000]
#define OFF_Q        6650016    // float[50000]
#define OFF_SCAL     6700016    // [0]=EminBits [1]=S0 [2]=S1
#define OFF_BLKSUM   6700020    // int[256]
#define OFF_ESRC     6700276    // int[640000] CSR-bucketed source ids

__global__ __launch_bounds__(256) void k_init(float* ws) {
    int i = blockIdx.x * 256 + threadIdx.x;
    if (i < N_NODES) ((int*)(ws + OFF_DEG))[i] = 0;
    if (i == 0) {
        ((int*)(ws + OFF_SCAL))[0] = 0x7F7FFFFF;  // FLT_MAX bits
        ws[OFF_SCAL + 1] = 0.f;
        ws[OFF_SCAL + 2] = 0.f;
    }
}

__global__ __launch_bounds__(256) void k_deg(const int* __restrict__ dst, int* __restrict__ deg) {
    int e = blockIdx.x * 256 + threadIdx.x;
    atomicAdd(&deg[dst[e]], 1);
}

// h = x @ W.  x:[N,128], W:[128,128]. 64x64 tile, 4x4 per thread.
__global__ __launch_bounds__(256) void k_gemm(const float* __restrict__ x,
                                              const float* __restrict__ W,
                                              float* __restrict__ h) {
    __shared__ float xs[64 * 132];
    __shared__ float wsm[128 * 64];
    int r0 = blockIdx.x * 64;
    int c0 = blockIdx.y * 64;
    int tid = threadIdx.x;

    #pragma unroll
    for (int i = 0; i < 8; i++) {
        int slot = tid + i * 256;
        int row = slot >> 5, k4 = slot & 31;
        float4 v = make_float4(0.f, 0.f, 0.f, 0.f);
        int gr = r0 + row;
        if (gr < N_NODES) v = *(const float4*)(x + gr * 128 + k4 * 4);
        *(float4*)(xs + row * 132 + k4 * 4) = v;
    }
    #pragma unroll
    for (int i = 0; i < 8; i++) {
        int slot = tid + i * 256;
        int k = slot >> 4, c4 = slot & 15;
        *(float4*)(wsm + k * 64 + c4 * 4) = *(const float4*)(W + k * 128 + c0 + c4 * 4);
    }
    __syncthreads();

    int tx = tid & 15, ty = tid >> 4;
    float acc[4][4];
    #pragma unroll
    for (int i = 0; i < 4; i++)
        #pragma unroll
        for (int j = 0; j < 4; j++) acc[i][j] = 0.f;

    for (int k = 0; k < 128; k++) {
        float4 wv = *(const float4*)(wsm + k * 64 + tx * 4);
        float xr[4];
        #pragma unroll
        for (int i = 0; i < 4; i++) xr[i] = xs[(ty * 4 + i) * 132 + k];
        #pragma unroll
        for (int i = 0; i < 4; i++) {
            acc[i][0] += xr[i] * wv.x;
            acc[i][1] += xr[i] * wv.y;
            acc[i][2] += xr[i] * wv.z;
            acc[i][3] += xr[i] * wv.w;
        }
    }
    #pragma unroll
    for (int i = 0; i < 4; i++) {
        int gr = r0 + ty * 4 + i;
        if (gr < N_NODES) {
            *(float4*)(h + gr * 128 + c0 + tx * 4) =
                make_float4(acc[i][0], acc[i][1], acc[i][2], acc[i][3]);
        }
    }
}

__global__ __launch_bounds__(256) void k_dinv(const int* __restrict__ deg, float* __restrict__ dinv) {
    int i = blockIdx.x * 256 + threadIdx.x;
    if (i < N_NODES) dinv[i] = rsqrtf((float)(deg[i] + 1));  // +1 self-loop
}

// ---- exclusive scan of deg -> rowstart (3 tiny kernels) ----
__global__ __launch_bounds__(256) void k_scan1(const int* __restrict__ deg,
                                               int* __restrict__ rowstart,
                                               int* __restrict__ blksum) {
    __shared__ int sh[256];
    int i = blockIdx.x * 256 + threadIdx.x;
    int v = (i < N_NODES) ? deg[i] : 0;
    sh[threadIdx.x] = v;
    __syncthreads();
    #pragma unroll
    for (int off = 1; off < 256; off <<= 1) {
        int t = (threadIdx.x >= off) ? sh[threadIdx.x - off] : 0;
        __syncthreads();
        sh[threadIdx.x] += t;
        __syncthreads();
    }
    if (i < N_NODES) rowstart[i] = sh[threadIdx.x] - v;  // exclusive
    if (threadIdx.x == 255) blksum[blockIdx.x] = sh[255];
}

__global__ __launch_bounds__(256) void k_scan2(int* __restrict__ blksum, int nblk) {
    __shared__ int sh[256];
    int tid = threadIdx.x;
    int v = (tid < nblk) ? blksum[tid] : 0;
    sh[tid] = v;
    __syncthreads();
    #pragma unroll
    for (int off = 1; off < 256; off <<= 1) {
        int t = (tid >= off) ? sh[tid - off] : 0;
        __syncthreads();
        sh[tid] += t;
        __syncthreads();
    }
    if (tid < nblk) blksum[tid] = sh[tid] - v;  // exclusive
}

__global__ __launch_bounds__(256) void k_scan3(int* __restrict__ rowstart,
                                               const int* __restrict__ blksum,
                                               int* __restrict__ cursor) {
    int i = blockIdx.x * 256 + threadIdx.x;
    if (i < N_NODES) {
        rowstart[i] += blksum[blockIdx.x];
        cursor[i] = 0;
    }
    if (i == 0) rowstart[N_NODES] = N_EDGES;
}

__global__ __launch_bounds__(256) void k_bucket(const int* __restrict__ src,
                                                const int* __restrict__ dst,
                                                const int* __restrict__ rowstart,
                                                int* __restrict__ cursor,
                                                int* __restrict__ esrc) {
    int e = blockIdx.x * 256 + threadIdx.x;
    int d = dst[e];
    int pos = atomicAdd(&cursor[d], 1);
    esrc[rowstart[d] + pos] = src[e];
}

// per node (32 lanes, float4/lane): out[d] = b + htmp[d]*dinv[d]^2 + sum htmp[s]*dinv[s]*dinv[d]
__global__ __launch_bounds__(256) void k_gather(const float* __restrict__ htmp,
                                                const float* __restrict__ dinv,
                                                const float* __restrict__ b,
                                                const int* __restrict__ rowstart,
                                                const int* __restrict__ esrc,
                                                float* __restrict__ out) {
    int node = blockIdx.x * 8 + (threadIdx.x >> 5);
    int lane = threadIdx.x & 31;
    if (node >= N_NODES) return;
    float di = dinv[node];
    float4 bv = *(const float4*)(b + lane * 4);
    float4 hv = *(const float4*)(htmp + node * 128 + lane * 4);
    float sl = di * di;
    float ax = bv.x + hv.x * sl, ay = bv.y + hv.y * sl;
    float az = bv.z + hv.z * sl, aw = bv.w + hv.w * sl;
    int e0 = rowstart[node], e1 = rowstart[node + 1];
    for (int k = e0; k < e1; k++) {
        int s = esrc[k];
        float norm = di * dinv[s];
        float4 v = *(const float4*)(htmp + s * 128 + lane * 4);
        ax += v.x * norm; ay += v.y * norm; az += v.z * norm; aw += v.w * norm;
    }
    *(float4*)(out + node * 128 + lane * 4) = make_float4(ax, ay, az, aw);
}

// per node: E[d] = sum_{edges into d} ||out[s]-out[d]||^2 (gather, no atomics)
__global__ __launch_bounds__(256) void k_energy2(const float* __restrict__ out,
                                                 const int* __restrict__ rowstart,
                                                 const int* __restrict__ esrc,
                                                 float* __restrict__ E) {
    int node = blockIdx.x * 8 + (threadIdx.x >> 5);
    int lane = threadIdx.x & 31;
    if (node >= N_NODES) return;
    float4 od = *(const float4*)(out + node * 128 + lane * 4);
    float acc = 0.f;
    int e0 = rowstart[node], e1 = rowstart[node + 1];
    for (int k = e0; k < e1; k++) {
        int s = esrc[k];
        float4 ov = *(const float4*)(out + s * 128 + lane * 4);
        float dx = ov.x - od.x, dy = ov.y - od.y, dz = ov.z - od.z, dw = ov.w - od.w;
        acc += dx * dx + dy * dy + dz * dz + dw * dw;
    }
    #pragma unroll
    for (int off = 16; off; off >>= 1) acc += __shfl_xor(acc, off);
    if (lane == 0) E[node] = acc;
}

__global__ __launch_bounds__(256) void k_emin(const float* __restrict__ E, int* __restrict__ scal) {
    __shared__ float sh[4];
    int i = blockIdx.x * 256 + threadIdx.x;
    float v = 3.402823466e38f;
    if (i < N_NODES) v = E[i];
    #pragma unroll
    for (int off = 32; off; off >>= 1) v = fminf(v, __shfl_xor(v, off));
    int lane = threadIdx.x & 63, wid = threadIdx.x >> 6;
    if (lane == 0) sh[wid] = v;
    __syncthreads();
    if (threadIdx.x == 0) {
        float m = fminf(fminf(sh[0], sh[1]), fminf(sh[2], sh[3]));
        atomicMin(scal, __float_as_int(m));  // valid: E >= 0
    }
}

__global__ __launch_bounds__(256) void k_sums(const float* __restrict__ E,
                                              const float* __restrict__ temp,
                                              const int* __restrict__ scal,
                                              float* __restrict__ S) {
    __shared__ float sh0[4], sh1[4];
    float Emin = __int_as_float(scal[0]);
    float T = temp[0];
    int i = blockIdx.x * 256 + threadIdx.x;
    float s0 = 0.f, s1 = 0.f;
    if (i < N_NODES) {
        float dd = (Emin - E[i]) / T;
        float ed = __expf(dd);
        s0 = ed; s1 = ed * dd;
    }
    #pragma unroll
    for (int off = 32; off; off >>= 1) { s0 += __shfl_xor(s0, off); s1 += __shfl_xor(s1, off); }
    int lane = threadIdx.x & 63, wid = threadIdx.x >> 6;
    if (lane == 0) { sh0[wid] = s0; sh1[wid] = s1; }
    __syncthreads();
    if (threadIdx.x == 0) {
        atomicAdd(&S[0], sh0[0] + sh0[1] + sh0[2] + sh0[3]);
        atomicAdd(&S[1], sh1[0] + sh1[1] + sh1[2] + sh1[3]);
    }
}

// q_i = (e^dd/S0)*(dd - S1/S0)/T,  dd=(Emin-E_i)/T
__global__ __launch_bounds__(256) void k_q(const float* __restrict__ E,
                                           const float* __restrict__ temp,
                                           const float* __restrict__ scal,
                                           float* __restrict__ q) {
    int i = blockIdx.x * 256 + threadIdx.x;
    if (i >= N_NODES) return;
    float Emin = __int_as_float(((const int*)scal)[0]);
    float S0 = scal[1], S1 = scal[2];
    float T = temp[0];
    float dd = (Emin - E[i]) / T;
    q[i] = (__expf(dd) / S0) * (dd - S1 / S0) / T;
}

// per edge: vec = 2*w*q[d]*(h_s - h_d); out[s] += vec; out[d] -= vec. Skip q==0 (most edges).
__global__ __launch_bounds__(256) void k_grad(const int* __restrict__ src,
                                              const int* __restrict__ dst,
                                              const float* __restrict__ q,
                                              const float* __restrict__ weight,
                                              float* __restrict__ out) {
    int gid = blockIdx.x * 256 + threadIdx.x;
    int e = gid >> 5, j4 = (gid & 31) * 4;
    int d = dst[e];
    float qd = q[d];
    if (qd == 0.f) return;
    int s = src[e];
    float c = 2.f * weight[0] * qd;
    float4 a = *(const float4*)(out + s * 128 + j4);
    float4 b = *(const float4*)(out + d * 128 + j4);
    float vx = c * (a.x - b.x), vy = c * (a.y - b.y), vz = c * (a.z - b.z), vw = c * (a.w - b.w);
    float* os = out + s * 128 + j4;
    float* od = out + d * 128 + j4;
    atomicAdd(os + 0, vx); atomicAdd(os + 1, vy); atomicAdd(os + 2, vz); atomicAdd(os + 3, vw);
    atomicAdd(od + 0, -vx); atomicAdd(od + 1, -vy); atomicAdd(od + 2, -vz); atomicAdd(od + 3, -vw);
}

extern "C" void kernel_launch(void* const* d_in, const int* in_sizes, int n_in,
                              void* d_out, int out_size, void* d_ws, size_t ws_size,
                              hipStream_t stream) {
    const float* x      = (const float*)d_in[0];
    const int*   ei     = (const int*)d_in[1];
    const float* weight = (const float*)d_in[2];
    const float* temp   = (const float*)d_in[3];
    const float* W      = (const float*)d_in[4];
    const float* b      = (const float*)d_in[5];
    float* out = (float*)d_out;
    float* ws  = (float*)d_ws;

    const int* src = ei;
    const int* dst = ei + N_EDGES;

    float* htmp     = ws + OFF_HTMP;
    int*   deg      = (int*)(ws + OFF_DEG);
    int*   rowstart = (int*)(ws + OFF_ROWSTART);
    int*   cursor   = (int*)(ws + OFF_CURSOR);
    float* dinv     = ws + OFF_DINV;
    float* Earr     = ws + OFF_E;
    float* qarr     = ws + OFF_Q;
    float* scal     = ws + OFF_SCAL;
    int*   blksum   = (int*)(ws + OFF_BLKSUM);
    int*   esrc     = (int*)(ws + OFF_ESRC);

    const int NBLK = 196;  // ceil(50000/256)

    k_init<<<NBLK, 256, 0, stream>>>(ws);
    k_deg<<<N_EDGES / 256, 256, 0, stream>>>(dst, deg);
    k_gemm<<<dim3(782, 2), 256, 0, stream>>>(x, W, htmp);
    k_dinv<<<NBLK, 256, 0, stream>>>(deg, dinv);
    k_scan1<<<NBLK, 256, 0, stream>>>(deg, rowstart, blksum);
    k_scan2<<<1, 256, 0, stream>>>(blksum, NBLK);
    k_scan3<<<NBLK, 256, 0, stream>>>(rowstart, blksum, cursor);
    k_bucket<<<N_EDGES / 256, 256, 0, stream>>>(src, dst, rowstart, cursor, esrc);
    k_gather<<<(N_NODES + 7) / 8, 256, 0, stream>>>(htmp, dinv, b, rowstart, esrc, out);
    k_energy2<<<(N_NODES + 7) / 8, 256, 0, stream>>>(out, rowstart, esrc, Earr);
    k_emin<<<NBLK, 256, 0, stream>>>(Earr, (int*)scal);
    k_sums<<<NBLK, 256, 0, stream>>>(Earr, temp, (const int*)scal, scal + 1);
    k_q<<<NBLK, 256, 0, stream>>>(Earr, temp, scal, qarr);
    k_grad<<<(N_EDGES * 32) / 256, 256, 0, stream>>>(src, dst, qarr, weight, out);
}